// Round 2
// baseline (1069.445 us; speedup 1.0000x reference)
//
#include <hip/hip_runtime.h>
#include <hip/hip_bf16.h>

#define T_ROWS 1000000
#define D 82
#define NG 256
#define ROWS_PER_BLOCK 64
#define TILE_FLOATS (ROWS_PER_BLOCK * D)      // 5248
#define TILE_F4     (TILE_FLOATS / 4)         // 1312 (exact: 5248 % 4 == 0)

// ws layout (float offsets): 6 per-group accumulators
#define WS_CNT 0
#define WS_SX  256
#define WS_SY  512
#define WS_SXY 768
#define WS_SXX 1024
#define WS_SYY 1280
#define WS_FLOATS 1536

// Fused kernel: coalesced staging of diff tile into LDS, per-row weighted
// sum-of-squares -> pred, plus one-pass per-group raw moment accumulation.
__global__ __launch_bounds__(256) void fused_kernel(
    const float* __restrict__ X1, const float* __restrict__ X2,
    const float* __restrict__ Y, const float* __restrict__ W,
    const int* __restrict__ mask, float* __restrict__ pred_out,
    float* __restrict__ ws)
{
    __shared__ float s_diff[TILE_FLOATS];     // 20992 B
    __shared__ float s_w[D];
    __shared__ float s_part[4][ROWS_PER_BLOCK];

    const int t = threadIdx.x;
    const size_t r0 = (size_t)blockIdx.x * ROWS_PER_BLOCK;
    const size_t base = r0 * D;               // float offset, 16B-aligned (5248*4 per block)

    const float4* __restrict__ a4 = (const float4*)(X1 + base);
    const float4* __restrict__ b4 = (const float4*)(X2 + base);
    float4* s4 = (float4*)s_diff;

    // Coalesced staging: lane i reads consecutive float4s of both matrices,
    // stores the difference. 1312 float4 per block / 256 threads.
    for (int i = t; i < TILE_F4; i += 256) {
        float4 a = a4[i];
        float4 b = b4[i];
        float4 d;
        d.x = a.x - b.x; d.y = a.y - b.y; d.z = a.z - b.z; d.w = a.w - b.w;
        s4[i] = d;
    }
    if (t < D) s_w[t] = W[t];
    __syncthreads();

    // Compute phase: wave q (q = t>>6) handles a wave-uniform k-range over
    // all 64 rows (row = t&63). w[k] is a same-address broadcast read.
    const int q = t >> 6;
    const int row = t & 63;
    const int start = (q < 2) ? q * 21 : 42 + (q - 2) * 20;
    const int len = (q < 2) ? 21 : 20;
    const float* __restrict__ dr = s_diff + row * D;
    float acc = 0.f;
    #pragma unroll 7
    for (int j = 0; j < len; ++j) {
        const int k = start + j;
        const float d = dr[k];
        acc += d * d * s_w[k];
    }
    s_part[q][row] = acc;
    __syncthreads();

    if (t < ROWS_PER_BLOCK) {
        const float s = s_part[0][t] + s_part[1][t] + s_part[2][t] + s_part[3][t];
        const float p = sqrtf(s);
        pred_out[r0 + t] = p;

        const int g = mask[r0 + t];
        const float y = Y[r0 + t];
        atomicAdd(&ws[WS_CNT + g], 1.0f);
        atomicAdd(&ws[WS_SX  + g], p);
        atomicAdd(&ws[WS_SY  + g], y);
        atomicAdd(&ws[WS_SXY + g], p * y);
        atomicAdd(&ws[WS_SXX + g], p * p);
        atomicAdd(&ws[WS_SYY + g], y * y);
    }
}

// Per-group Pearson |r| from raw moments (f64 combine), block-reduce, mean.
__global__ void final_kernel(const float* __restrict__ ws, float* __restrict__ out)
{
    __shared__ float red[NG];
    const int g = threadIdx.x;
    const double n   = (double)ws[WS_CNT + g];
    const double sx  = (double)ws[WS_SX  + g];
    const double sy  = (double)ws[WS_SY  + g];
    const double sxy = (double)ws[WS_SXY + g];
    const double sxx = (double)ws[WS_SXX + g];
    const double syy = (double)ws[WS_SYY + g];
    const double num  = n * sxy - sx * sy;
    const double varx = n * sxx - sx * sx;
    const double vary = n * syy - sy * sy;
    red[g] = (float)fabs(num / sqrt(varx * vary));
    __syncthreads();
    for (int s = 128; s > 0; s >>= 1) {
        if (g < s) red[g] += red[g + s];
        __syncthreads();
    }
    if (g == 0) out[0] = red[0] / (float)NG;
}

extern "C" void kernel_launch(void* const* d_in, const int* in_sizes, int n_in,
                              void* d_out, int out_size, void* d_ws, size_t ws_size,
                              hipStream_t stream)
{
    const float* X1   = (const float*)d_in[0];
    const float* X2   = (const float*)d_in[1];
    const float* Y    = (const float*)d_in[2];
    const float* W    = (const float*)d_in[3];
    const int*   mask = (const int*)d_in[4];
    float* out = (float*)d_out;
    float* ws  = (float*)d_ws;

    hipMemsetAsync(ws, 0, WS_FLOATS * sizeof(float), stream);

    const int grid = T_ROWS / ROWS_PER_BLOCK;   // 15625 exactly
    fused_kernel<<<grid, 256, 0, stream>>>(X1, X2, Y, W, mask, out + 1, ws);
    final_kernel<<<1, NG, 0, stream>>>(ws, out);
}